// Round 4
// baseline (179.069 us; speedup 1.0000x reference)
//
#include <hip/hip_runtime.h>

// Eq2NetSet via fp16 MFMA (16x16x32, fp32 accum).
// R9: merge reduce_decode into pair_mlp via last-block-per-batch ticket
// (threadfence reduction pattern). Removes one kernel launch + the 4-block
// latency-bound reduce kernel; 4 reducer tails overlap with straggler blocks.
// Tickets re-zeroed by prep each iteration (graph-replay safe).
// R6-R8 base: fp16 pipeline (v_pk_mul_f16 P-build, v_cvt_pkrtz epilogue packs,
// tri_ij LUT), channels = M, pairs = N, 128 triangle pairs per block.
//   L1: H1^T = W1^T (A) @ P^T (B),  K=64
//   L2: H2^T = W2^T @ H1^T,         K=128
//   L3: H3^T = W3^T @ H2^T,         K=128 -> relu -> weighted pair-sum

#define NB 4
#define NN 256
#define HD 128
#define TPB 257      // tiles per batch: 32896 pairs / 128
#define NPAIR 32896  // 256*257/2

typedef _Float16 half_t;
typedef __attribute__((ext_vector_type(8))) _Float16 half8;
typedef __attribute__((ext_vector_type(4))) float f32x4;

// packed fp16 pair from two fp32 (single v_cvt_pkrtz_f16_f32)
__device__ __forceinline__ unsigned pkrtz(float a, float b) {
    return __builtin_bit_cast(unsigned, __builtin_amdgcn_cvt_pkrtz(a, b));
}

__device__ __forceinline__ void tri_ij(int t, int& i, int& j) {
    j = (int)((sqrtf(8.0f * (float)t + 1.0f) - 1.0f) * 0.5f);
    while (((j + 1) * (j + 2) >> 1) <= t) ++j;
    while (((j * (j + 1)) >> 1) > t) --j;
    i = t - ((j * (j + 1)) >> 1);
}

// pack W[fanin][128] into A-fragment-linear fp16: packed[(mt*KQ+kq)*64 + lane][j],
// value = W[kq*32 + (lane>>4)*8 + j][mt*16 + (lane&15)]
__device__ __forceinline__ void pack_w(const float* __restrict__ W, half_t* __restrict__ pw,
                                       int KQ, int u) {
    int l  = u & 63;
    int kq = (u >> 6) % KQ;
    int mt = (u >> 6) / KQ;
    int q = l >> 4, m = l & 15;
    int c = mt * 16 + m;
#pragma unroll
    for (int j = 0; j < 8; ++j) {
        int k = kq * 32 + q * 8 + j;
        pw[u * 8 + j] = (half_t)W[k * 128 + c];
    }
}

__global__ void prep_kernel(const int* __restrict__ xcat,
                            const float* __restrict__ xfeat,
                            const float* __restrict__ emb,
                            const float* __restrict__ W1,
                            const float* __restrict__ W2,
                            const float* __restrict__ W3,
                            half_t* __restrict__ x,
                            half_t* __restrict__ pw1,
                            half_t* __restrict__ pw2,
                            half_t* __restrict__ pw3,
                            unsigned short* __restrict__ lut,
                            int* __restrict__ ticket)
{
    int bid = blockIdx.x;
    int tid = threadIdx.x;
    if (bid < 256) {                       // build x[4][256][64] fp16
        int f = bid * 256 + tid;
        int d = f & 63;
        int nn = f >> 6;                   // b*256+n
        float v;
        if (d < 63) v = emb[xcat[nn] * 63 + d];
        else        v = xfeat[nn];
        x[f] = (half_t)v;
    } else if (bid < 260) {                // W1: 8mt*2kq*64 = 1024 threads
        pack_w(W1, pw1, 2, (bid - 256) * 256 + tid);
    } else if (bid < 268) {                // W2: 8mt*4kq*64 = 2048
        pack_w(W2, pw2, 4, (bid - 260) * 256 + tid);
    } else if (bid < 276) {                // W3
        pack_w(W3, pw3, 4, (bid - 268) * 256 + tid);
    } else {                               // triangle (i,j) LUT: 129 blocks
        int t = (bid - 276) * 256 + tid;
        if (t < NPAIR) {
            int i, j;
            tri_ij(t, i, j);
            lut[t] = (unsigned short)(i | (j << 8));
        }
        if (bid == 276 && tid < NB) ticket[tid] = 0;   // re-zero every iteration
    }
}

__global__ __launch_bounds__(256, 3) void pair_mlp(
    const half_t* __restrict__ x,
    const unsigned short* __restrict__ lut,
    const half_t* __restrict__ pw1, const float* __restrict__ b1,
    const half_t* __restrict__ pw2, const float* __restrict__ b2,
    const half_t* __restrict__ pw3, const float* __restrict__ b3,
    float* __restrict__ partialOut,
    int* __restrict__ ticket,
    const float* __restrict__ D1, const float* __restrict__ c1,
    const float* __restrict__ D2, const float* __restrict__ c2,
    const float* __restrict__ D3, const float* __restrict__ c3,
    float* __restrict__ out)
{
    __shared__ half_t smP[128 * 64];    // 16 KB  P^T tile, row=pair, 64 f16 (8 chunks)
    __shared__ half_t smH[128 * 128];   // 32 KB  H tile,   row=pair, 128 f16 (16 chunks)
    __shared__ float smW[128];          // pair weights (1 diag / 2 off-diag)
    __shared__ int isLast;

    const int tid = threadIdx.x;
    const int l = tid & 63;
    const int w = __builtin_amdgcn_readfirstlane(tid >> 6);  // wave 0..3
    const int wm = w >> 1;             // channel half: mt in [wm*4, wm*4+4)
    const int wn = w & 1;              // pair half:    pairs [wn*64, wn*64+64)
    const int q = l >> 4;
    const int m = l & 15;
    const int b = blockIdx.y;
    const int tbase = blockIdx.x * 128;          // triangle index base for this tile
    const half_t* xb = x + (b << 14);
    char* smPc = (char*)smP;
    char* smHc = (char*)smH;

    // ---- build P^T tile: 256 threads, thread = (pair p = tid>>1, half = tid&1) ----
    {
        const int p = tid >> 1;
        const int hf = tid & 1;
        unsigned short ij = lut[tbase + p];
        int i = ij & 255, j = ij >> 8;
        if (hf == 0) smW[p] = (i == j) ? 1.0f : 2.0f;
        const half8* xi = (const half8*)(xb + (i << 6) + hf * 32);
        const half8* xj = (const half8*)(xb + (j << 6) + hf * 32);
#pragma unroll
        for (int c = 0; c < 4; ++c) {
            half8 s = xi[c] * xj[c];           // 4x v_pk_mul_f16
            int chunk = hf * 4 + c;
            int phys = chunk ^ (p & 7);
            *(uint4*)(smPc + p * 128 + phys * 16) = __builtin_bit_cast(uint4, s);
        }
    }
    __syncthreads();

    f32x4 acc[4][4];

    // ---- L1: K=64, B from smP, acc init = b1 (bias fold) ----
#pragma unroll
    for (int mt = 0; mt < 4; ++mt) {
        float4 bv = *(const float4*)(b1 + (wm * 4 + mt) * 16 + q * 4);
        f32x4 init = {bv.x, bv.y, bv.z, bv.w};
#pragma unroll
        for (int nt = 0; nt < 4; ++nt) acc[mt][nt] = init;
    }

#pragma unroll
    for (int kq = 0; kq < 2; ++kq) {
        half8 bfr[4], afr[4];
#pragma unroll
        for (int nt = 0; nt < 4; ++nt) {
            int pair = wn * 64 + nt * 16 + m;
            int phys = (kq * 4 + q) ^ (pair & 7);
            bfr[nt] = *(const half8*)(smPc + pair * 128 + phys * 16);
        }
#pragma unroll
        for (int mt = 0; mt < 4; ++mt)
            afr[mt] = *(const half8*)(pw1 + ((((wm * 4 + mt) * 2 + kq) * 64 + l) << 3));
#pragma unroll
        for (int mt = 0; mt < 4; ++mt)
#pragma unroll
            for (int nt = 0; nt < 4; ++nt)
                acc[mt][nt] = __builtin_amdgcn_mfma_f32_16x16x32_f16(afr[mt], bfr[nt], acc[mt][nt], 0, 0, 0);
    }

    // epilogue L1 -> smH (relu + pkrtz f16 pack), swizzled 8B writes
#pragma unroll
    for (int mt = 0; mt < 4; ++mt) {
        int mtg = wm * 4 + mt;
#pragma unroll
        for (int nt = 0; nt < 4; ++nt) {
            int pair = wn * 64 + nt * 16 + m;
            uint2 sv;
            sv.x = pkrtz(fmaxf(acc[mt][nt][0], 0.f), fmaxf(acc[mt][nt][1], 0.f));
            sv.y = pkrtz(fmaxf(acc[mt][nt][2], 0.f), fmaxf(acc[mt][nt][3], 0.f));
            int chunk = mtg * 2 + (q >> 1);
            int phys = chunk ^ (pair & 15);
            *(uint2*)(smHc + pair * 256 + phys * 16 + (q & 1) * 8) = sv;
        }
    }
    __syncthreads();

    // ---- L2: K=128, B from smH (H1), acc init = b2 ----
#pragma unroll
    for (int mt = 0; mt < 4; ++mt) {
        float4 bv = *(const float4*)(b2 + (wm * 4 + mt) * 16 + q * 4);
        f32x4 init = {bv.x, bv.y, bv.z, bv.w};
#pragma unroll
        for (int nt = 0; nt < 4; ++nt) acc[mt][nt] = init;
    }

#pragma unroll
    for (int kq = 0; kq < 4; ++kq) {
        half8 bfr[4], afr[4];
#pragma unroll
        for (int nt = 0; nt < 4; ++nt) {
            int pair = wn * 64 + nt * 16 + m;
            int phys = (kq * 4 + q) ^ (pair & 15);
            bfr[nt] = *(const half8*)(smHc + pair * 256 + phys * 16);
        }
#pragma unroll
        for (int mt = 0; mt < 4; ++mt)
            afr[mt] = *(const half8*)(pw2 + ((((wm * 4 + mt) * 4 + kq) * 64 + l) << 3));
#pragma unroll
        for (int mt = 0; mt < 4; ++mt)
#pragma unroll
            for (int nt = 0; nt < 4; ++nt)
                acc[mt][nt] = __builtin_amdgcn_mfma_f32_16x16x32_f16(afr[mt], bfr[nt], acc[mt][nt], 0, 0, 0);
    }
    __syncthreads();   // all reads of H1 done before overwriting smH

    // epilogue L2 -> smH (H2)
#pragma unroll
    for (int mt = 0; mt < 4; ++mt) {
        int mtg = wm * 4 + mt;
#pragma unroll
        for (int nt = 0; nt < 4; ++nt) {
            int pair = wn * 64 + nt * 16 + m;
            uint2 sv;
            sv.x = pkrtz(fmaxf(acc[mt][nt][0], 0.f), fmaxf(acc[mt][nt][1], 0.f));
            sv.y = pkrtz(fmaxf(acc[mt][nt][2], 0.f), fmaxf(acc[mt][nt][3], 0.f));
            int chunk = mtg * 2 + (q >> 1);
            int phys = chunk ^ (pair & 15);
            *(uint2*)(smHc + pair * 256 + phys * 16 + (q & 1) * 8) = sv;
        }
    }
    __syncthreads();

    // ---- L3: K=128, B from smH (H2), acc init = b3 ----
#pragma unroll
    for (int mt = 0; mt < 4; ++mt) {
        float4 bv = *(const float4*)(b3 + (wm * 4 + mt) * 16 + q * 4);
        f32x4 init = {bv.x, bv.y, bv.z, bv.w};
#pragma unroll
        for (int nt = 0; nt < 4; ++nt) acc[mt][nt] = init;
    }

#pragma unroll
    for (int kq = 0; kq < 4; ++kq) {
        half8 bfr[4], afr[4];
#pragma unroll
        for (int nt = 0; nt < 4; ++nt) {
            int pair = wn * 64 + nt * 16 + m;
            int phys = (kq * 4 + q) ^ (pair & 15);
            bfr[nt] = *(const half8*)(smHc + pair * 256 + phys * 16);
        }
#pragma unroll
        for (int mt = 0; mt < 4; ++mt)
            afr[mt] = *(const half8*)(pw3 + ((((wm * 4 + mt) * 4 + kq) * 64 + l) << 3));
#pragma unroll
        for (int mt = 0; mt < 4; ++mt)
#pragma unroll
            for (int nt = 0; nt < 4; ++nt)
                acc[mt][nt] = __builtin_amdgcn_mfma_f32_16x16x32_f16(afr[mt], bfr[nt], acc[mt][nt], 0, 0, 0);
    }

    // ---- reduction: relu(h3) * pair-weight, sum over pairs -> LDS -> partial ----
    float wpv[4];
#pragma unroll
    for (int nt = 0; nt < 4; ++nt)
        wpv[nt] = smW[wn * 64 + nt * 16 + m];

    float* smPart = (float*)smP;   // 256 floats; smP dead since L1
#pragma unroll
    for (int mt = 0; mt < 4; ++mt) {
        int mtg = wm * 4 + mt;
        float vs[4];
#pragma unroll
        for (int r = 0; r < 4; ++r) {
            vs[r] = wpv[0] * fmaxf(acc[mt][0][r], 0.f) + wpv[1] * fmaxf(acc[mt][1][r], 0.f)
                  + wpv[2] * fmaxf(acc[mt][2][r], 0.f) + wpv[3] * fmaxf(acc[mt][3][r], 0.f);
#pragma unroll
            for (int s = 1; s < 16; s <<= 1)
                vs[r] += __shfl_xor(vs[r], s, 64);
        }
        if (m == 0) {
            float* p = smPart + wn * HD + mtg * 16 + q * 4;
            p[0] = vs[0]; p[1] = vs[1]; p[2] = vs[2]; p[3] = vs[3];
        }
    }
    __syncthreads();

    if (tid < HD) {
        float v = smPart[tid] + smPart[HD + tid];
        partialOut[(b * TPB + blockIdx.x) * HD + tid] = v;   // coalesced 512B/block
    }

    // ---- ticket: last block of batch b does the reduce + decode tail ----
    __threadfence();                       // release partial writes
    __syncthreads();                       // all writes + fences before the atomic
    if (tid == 0)
        isLast = (atomicAdd(&ticket[b], 1) == TPB - 1);
    __syncthreads();
    if (!isLast) return;
    __threadfence();                       // acquire side

    // tail: 256 threads. ch = tid&127, sl = tid>>7 (2 slices). LDS reuse of smP.
    float* redA = (float*)smP;             // [2][HD]
    float* hb   = redA + 2 * HD;           // [HD]
    float* tb   = hb + HD;                 // [HD]
    float* red2 = tb + HD;                 // [2][HD]
    const int ch = tid & 127, sl = tid >> 7;

    // Phase A: sum 257 tile-partials per channel (2 slices, unroll x4)
    {
        const float* basep = partialOut + b * TPB * HD + ch;
        float s0 = 0.f, s1 = 0.f, s2 = 0.f, s3 = 0.f;
        int tl = sl;
        for (; tl + 8 <= TPB; tl += 8) {
            s0 += basep[(tl    ) * HD];
            s1 += basep[(tl + 2) * HD];
            s2 += basep[(tl + 4) * HD];
            s3 += basep[(tl + 6) * HD];
        }
        for (; tl < TPB; tl += 2) s0 += basep[tl * HD];
        redA[sl * HD + ch] = (s0 + s1) + (s2 + s3);
    }
    __syncthreads();
    if (sl == 0)
        hb[ch] = fmaxf((redA[ch] + redA[HD + ch]) * (1.0f / 65536.0f), 0.0f);
    __syncthreads();

    // dec layer 1 (split-k over 2 halves)
    {
        float a = 0.f;
        for (int k = sl * 64; k < sl * 64 + 64; ++k)
            a = fmaf(hb[k], D1[(k << 7) + ch], a);
        red2[sl * HD + ch] = a;
    }
    __syncthreads();
    if (sl == 0)
        tb[ch] = fmaxf(red2[ch] + red2[HD + ch] + c1[ch], 0.0f);
    __syncthreads();

    // dec layer 2
    {
        float a = 0.f;
        for (int k = sl * 64; k < sl * 64 + 64; ++k)
            a = fmaf(tb[k], D2[(k << 7) + ch], a);
        red2[sl * HD + ch] = a;
    }
    __syncthreads();
    if (sl == 0)
        hb[ch] = fmaxf(red2[ch] + red2[HD + ch] + c2[ch], 0.0f);
    __syncthreads();

    // dec layer 3: out[b] = dot(hb, D3) + c3
    if (sl == 0) red2[ch] = hb[ch] * D3[ch];
    __syncthreads();
    if (tid < 64) {
        float r = red2[tid] + red2[tid + 64];
#pragma unroll
        for (int sv = 1; sv < 64; sv <<= 1)
            r += __shfl_xor(r, sv, 64);
        if (tid == 0) out[b] = r + c3[0];
    }
}

extern "C" void kernel_launch(void* const* d_in, const int* in_sizes, int n_in,
                              void* d_out, int out_size, void* d_ws, size_t ws_size,
                              hipStream_t stream)
{
    (void)in_sizes; (void)n_in; (void)out_size; (void)ws_size;

    const int*   xcat  = (const int*)  d_in[0];
    const float* xfeat = (const float*)d_in[1];
    const float* emb   = (const float*)d_in[2];
    const float* W1    = (const float*)d_in[3];
    const float* b1    = (const float*)d_in[4];
    const float* W2    = (const float*)d_in[5];
    const float* b2    = (const float*)d_in[6];
    const float* W3    = (const float*)d_in[7];
    const float* b3    = (const float*)d_in[8];
    const float* D1    = (const float*)d_in[9];
    const float* c1    = (const float*)d_in[10];
    const float* D2    = (const float*)d_in[11];
    const float* c2    = (const float*)d_in[12];
    const float* D3    = (const float*)d_in[13];
    const float* c3    = (const float*)d_in[14];
    float* out = (float*)d_out;

    half_t* x   = (half_t*)d_ws;                      // 65536 h
    half_t* pw1 = x + NB * NN * 64;                   // 8192 h
    half_t* pw2 = pw1 + 8 * 2 * 64 * 8;               // 16384 h
    half_t* pw3 = pw2 + 8 * 4 * 64 * 8;               // 16384 h
    unsigned short* lut = (unsigned short*)(pw3 + 8 * 4 * 64 * 8);  // 32896 us
    float* partial = (float*)(lut + NPAIR);           // 4*257*128 f
    int* ticket = (int*)(partial + NB * TPB * HD);    // 4 ints

    prep_kernel<<<405, 256, 0, stream>>>(xcat, xfeat, emb, W1, W2, W3,
                                         x, pw1, pw2, pw3, lut, ticket);
    pair_mlp<<<dim3(TPB, NB), 256, 0, stream>>>(x, lut, pw1, b1, pw2, b2, pw3, b3,
                                                partial, ticket,
                                                D1, c1, D2, c2, D3, c3, out);
}

// Round 5
// 118.881 us; speedup vs baseline: 1.5063x; 1.5063x over previous
//
#include <hip/hip_runtime.h>

// Eq2NetSet via fp16 MFMA (16x16x32, fp32 accum).
// R10: revert R9's ticket merge (per-block __threadfence = device-scope L2
// writeback per block on non-coherent XCDs -> 103us idle kernel. Kernel
// boundary IS the cheap device-wide release; keep 3 kernels).
// New in R10: smP overlaid on smH (smP live only until end of L1 k-loop;
// +1 barrier before L1 epilogue, +1 after L3 loop). LDS 49.6 -> 33.3 KB
// -> 4 blocks/CU (was 3): 1024/1028 blocks co-resident, 16 waves/CU.
// R6-R8 base: fp16 pipeline (v_pk_mul_f16 P-build, v_cvt_pkrtz epilogue
// packs, tri_ij LUT), channels = M, pairs = N, 128 triangle pairs/block.
//   L1: H1^T = W1^T (A) @ P^T (B),  K=64
//   L2: H2^T = W2^T @ H1^T,         K=128
//   L3: H3^T = W3^T @ H2^T,         K=128 -> relu -> weighted pair-sum

#define NB 4
#define NN 256
#define HD 128
#define TPB 257      // tiles per batch: 32896 pairs / 128
#define NPAIR 32896  // 256*257/2

typedef _Float16 half_t;
typedef __attribute__((ext_vector_type(8))) _Float16 half8;
typedef __attribute__((ext_vector_type(4))) float f32x4;

// packed fp16 pair from two fp32 (single v_cvt_pkrtz_f16_f32)
__device__ __forceinline__ unsigned pkrtz(float a, float b) {
    return __builtin_bit_cast(unsigned, __builtin_amdgcn_cvt_pkrtz(a, b));
}

__device__ __forceinline__ void tri_ij(int t, int& i, int& j) {
    j = (int)((sqrtf(8.0f * (float)t + 1.0f) - 1.0f) * 0.5f);
    while (((j + 1) * (j + 2) >> 1) <= t) ++j;
    while (((j * (j + 1)) >> 1) > t) --j;
    i = t - ((j * (j + 1)) >> 1);
}

// pack W[fanin][128] into A-fragment-linear fp16: packed[(mt*KQ+kq)*64 + lane][j],
// value = W[kq*32 + (lane>>4)*8 + j][mt*16 + (lane&15)]
__device__ __forceinline__ void pack_w(const float* __restrict__ W, half_t* __restrict__ pw,
                                       int KQ, int u) {
    int l  = u & 63;
    int kq = (u >> 6) % KQ;
    int mt = (u >> 6) / KQ;
    int q = l >> 4, m = l & 15;
    int c = mt * 16 + m;
#pragma unroll
    for (int j = 0; j < 8; ++j) {
        int k = kq * 32 + q * 8 + j;
        pw[u * 8 + j] = (half_t)W[k * 128 + c];
    }
}

__global__ void prep_kernel(const int* __restrict__ xcat,
                            const float* __restrict__ xfeat,
                            const float* __restrict__ emb,
                            const float* __restrict__ W1,
                            const float* __restrict__ W2,
                            const float* __restrict__ W3,
                            half_t* __restrict__ x,
                            half_t* __restrict__ pw1,
                            half_t* __restrict__ pw2,
                            half_t* __restrict__ pw3,
                            unsigned short* __restrict__ lut)
{
    int bid = blockIdx.x;
    int tid = threadIdx.x;
    if (bid < 256) {                       // build x[4][256][64] fp16
        int f = bid * 256 + tid;
        int d = f & 63;
        int nn = f >> 6;                   // b*256+n
        float v;
        if (d < 63) v = emb[xcat[nn] * 63 + d];
        else        v = xfeat[nn];
        x[f] = (half_t)v;
    } else if (bid < 260) {                // W1: 8mt*2kq*64 = 1024 threads
        pack_w(W1, pw1, 2, (bid - 256) * 256 + tid);
    } else if (bid < 268) {                // W2: 8mt*4kq*64 = 2048
        pack_w(W2, pw2, 4, (bid - 260) * 256 + tid);
    } else if (bid < 276) {                // W3
        pack_w(W3, pw3, 4, (bid - 268) * 256 + tid);
    } else {                               // triangle (i,j) LUT: 129 blocks
        int t = (bid - 276) * 256 + tid;
        if (t < NPAIR) {
            int i, j;
            tri_ij(t, i, j);
            lut[t] = (unsigned short)(i | (j << 8));
        }
    }
}

__global__ __launch_bounds__(256, 4) void pair_mlp(
    const half_t* __restrict__ x,
    const unsigned short* __restrict__ lut,
    const half_t* __restrict__ pw1, const float* __restrict__ b1,
    const half_t* __restrict__ pw2, const float* __restrict__ b2,
    const half_t* __restrict__ pw3, const float* __restrict__ b3,
    float* __restrict__ partialOut)
{
    // 32 KB unified buffer: P^T tile (first 16 KB) is overlaid on the H tile.
    // P live: P-build .. end of L1 k-loop (barrier before L1 epilogue).
    // smPart (1 KB at base) live: after post-L3 barrier.
    __shared__ char smBuf[128 * 256];
    __shared__ float smW[128];          // pair weights (1 diag / 2 off-diag)

    const int tid = threadIdx.x;
    const int l = tid & 63;
    const int w = __builtin_amdgcn_readfirstlane(tid >> 6);  // wave 0..3
    const int wm = w >> 1;             // channel half: mt in [wm*4, wm*4+4)
    const int wn = w & 1;              // pair half:    pairs [wn*64, wn*64+64)
    const int q = l >> 4;
    const int m = l & 15;
    const int b = blockIdx.y;
    const int tbase = blockIdx.x * 128;          // triangle index base for this tile
    const half_t* xb = x + (b << 14);
    char* smPc = smBuf;
    char* smHc = smBuf;

    // ---- build P^T tile: 256 threads, thread = (pair p = tid>>1, half = tid&1) ----
    {
        const int p = tid >> 1;
        const int hf = tid & 1;
        unsigned short ij = lut[tbase + p];
        int i = ij & 255, j = ij >> 8;
        if (hf == 0) smW[p] = (i == j) ? 1.0f : 2.0f;
        const half8* xi = (const half8*)(xb + (i << 6) + hf * 32);
        const half8* xj = (const half8*)(xb + (j << 6) + hf * 32);
#pragma unroll
        for (int c = 0; c < 4; ++c) {
            half8 s = xi[c] * xj[c];           // 4x v_pk_mul_f16
            int chunk = hf * 4 + c;
            int phys = chunk ^ (p & 7);
            *(uint4*)(smPc + p * 128 + phys * 16) = __builtin_bit_cast(uint4, s);
        }
    }
    __syncthreads();

    f32x4 acc[4][4];

    // ---- L1: K=64, B from smP, acc init = b1 (bias fold) ----
#pragma unroll
    for (int mt = 0; mt < 4; ++mt) {
        float4 bv = *(const float4*)(b1 + (wm * 4 + mt) * 16 + q * 4);
        f32x4 init = {bv.x, bv.y, bv.z, bv.w};
#pragma unroll
        for (int nt = 0; nt < 4; ++nt) acc[mt][nt] = init;
    }

#pragma unroll
    for (int kq = 0; kq < 2; ++kq) {
        half8 bfr[4], afr[4];
#pragma unroll
        for (int nt = 0; nt < 4; ++nt) {
            int pair = wn * 64 + nt * 16 + m;
            int phys = (kq * 4 + q) ^ (pair & 7);
            bfr[nt] = *(const half8*)(smPc + pair * 128 + phys * 16);
        }
#pragma unroll
        for (int mt = 0; mt < 4; ++mt)
            afr[mt] = *(const half8*)(pw1 + ((((wm * 4 + mt) * 2 + kq) * 64 + l) << 3));
#pragma unroll
        for (int mt = 0; mt < 4; ++mt)
#pragma unroll
            for (int nt = 0; nt < 4; ++nt)
                acc[mt][nt] = __builtin_amdgcn_mfma_f32_16x16x32_f16(afr[mt], bfr[nt], acc[mt][nt], 0, 0, 0);
    }
    __syncthreads();   // NEW: all waves done reading P before epilogue clobbers it

    // epilogue L1 -> smH (relu + pkrtz f16 pack), swizzled 8B writes
#pragma unroll
    for (int mt = 0; mt < 4; ++mt) {
        int mtg = wm * 4 + mt;
#pragma unroll
        for (int nt = 0; nt < 4; ++nt) {
            int pair = wn * 64 + nt * 16 + m;
            uint2 sv;
            sv.x = pkrtz(fmaxf(acc[mt][nt][0], 0.f), fmaxf(acc[mt][nt][1], 0.f));
            sv.y = pkrtz(fmaxf(acc[mt][nt][2], 0.f), fmaxf(acc[mt][nt][3], 0.f));
            int chunk = mtg * 2 + (q >> 1);
            int phys = chunk ^ (pair & 15);
            *(uint2*)(smHc + pair * 256 + phys * 16 + (q & 1) * 8) = sv;
        }
    }
    __syncthreads();

    // ---- L2: K=128, B from smH (H1), acc init = b2 ----
#pragma unroll
    for (int mt = 0; mt < 4; ++mt) {
        float4 bv = *(const float4*)(b2 + (wm * 4 + mt) * 16 + q * 4);
        f32x4 init = {bv.x, bv.y, bv.z, bv.w};
#pragma unroll
        for (int nt = 0; nt < 4; ++nt) acc[mt][nt] = init;
    }

#pragma unroll
    for (int kq = 0; kq < 4; ++kq) {
        half8 bfr[4], afr[4];
#pragma unroll
        for (int nt = 0; nt < 4; ++nt) {
            int pair = wn * 64 + nt * 16 + m;
            int phys = (kq * 4 + q) ^ (pair & 15);
            bfr[nt] = *(const half8*)(smHc + pair * 256 + phys * 16);
        }
#pragma unroll
        for (int mt = 0; mt < 4; ++mt)
            afr[mt] = *(const half8*)(pw2 + ((((wm * 4 + mt) * 4 + kq) * 64 + l) << 3));
#pragma unroll
        for (int mt = 0; mt < 4; ++mt)
#pragma unroll
            for (int nt = 0; nt < 4; ++nt)
                acc[mt][nt] = __builtin_amdgcn_mfma_f32_16x16x32_f16(afr[mt], bfr[nt], acc[mt][nt], 0, 0, 0);
    }
    __syncthreads();   // all reads of H1 done before overwriting smH

    // epilogue L2 -> smH (H2)
#pragma unroll
    for (int mt = 0; mt < 4; ++mt) {
        int mtg = wm * 4 + mt;
#pragma unroll
        for (int nt = 0; nt < 4; ++nt) {
            int pair = wn * 64 + nt * 16 + m;
            uint2 sv;
            sv.x = pkrtz(fmaxf(acc[mt][nt][0], 0.f), fmaxf(acc[mt][nt][1], 0.f));
            sv.y = pkrtz(fmaxf(acc[mt][nt][2], 0.f), fmaxf(acc[mt][nt][3], 0.f));
            int chunk = mtg * 2 + (q >> 1);
            int phys = chunk ^ (pair & 15);
            *(uint2*)(smHc + pair * 256 + phys * 16 + (q & 1) * 8) = sv;
        }
    }
    __syncthreads();

    // ---- L3: K=128, B from smH (H2), acc init = b3 ----
#pragma unroll
    for (int mt = 0; mt < 4; ++mt) {
        float4 bv = *(const float4*)(b3 + (wm * 4 + mt) * 16 + q * 4);
        f32x4 init = {bv.x, bv.y, bv.z, bv.w};
#pragma unroll
        for (int nt = 0; nt < 4; ++nt) acc[mt][nt] = init;
    }

#pragma unroll
    for (int kq = 0; kq < 4; ++kq) {
        half8 bfr[4], afr[4];
#pragma unroll
        for (int nt = 0; nt < 4; ++nt) {
            int pair = wn * 64 + nt * 16 + m;
            int phys = (kq * 4 + q) ^ (pair & 15);
            bfr[nt] = *(const half8*)(smHc + pair * 256 + phys * 16);
        }
#pragma unroll
        for (int mt = 0; mt < 4; ++mt)
            afr[mt] = *(const half8*)(pw3 + ((((wm * 4 + mt) * 4 + kq) * 64 + l) << 3));
#pragma unroll
        for (int mt = 0; mt < 4; ++mt)
#pragma unroll
            for (int nt = 0; nt < 4; ++nt)
                acc[mt][nt] = __builtin_amdgcn_mfma_f32_16x16x32_f16(afr[mt], bfr[nt], acc[mt][nt], 0, 0, 0);
    }
    __syncthreads();   // NEW: all waves done reading smH before smPart overlay writes

    // ---- reduction: relu(h3) * pair-weight, sum over pairs -> LDS -> partial ----
    float wpv[4];
#pragma unroll
    for (int nt = 0; nt < 4; ++nt)
        wpv[nt] = smW[wn * 64 + nt * 16 + m];

    float* smPart = (float*)smBuf;   // 256 floats at base; smH reads done
#pragma unroll
    for (int mt = 0; mt < 4; ++mt) {
        int mtg = wm * 4 + mt;
        float vs[4];
#pragma unroll
        for (int r = 0; r < 4; ++r) {
            vs[r] = wpv[0] * fmaxf(acc[mt][0][r], 0.f) + wpv[1] * fmaxf(acc[mt][1][r], 0.f)
                  + wpv[2] * fmaxf(acc[mt][2][r], 0.f) + wpv[3] * fmaxf(acc[mt][3][r], 0.f);
#pragma unroll
            for (int s = 1; s < 16; s <<= 1)
                vs[r] += __shfl_xor(vs[r], s, 64);
        }
        if (m == 0) {
            float* p = smPart + wn * HD + mtg * 16 + q * 4;
            p[0] = vs[0]; p[1] = vs[1]; p[2] = vs[2]; p[3] = vs[3];
        }
    }
    __syncthreads();

    if (tid < HD) {
        float v = smPart[tid] + smPart[HD + tid];
        partialOut[(b * TPB + blockIdx.x) * HD + tid] = v;   // coalesced 512B/block
    }
}

// fused reduce + decoder: one block per batch, 1024 threads.
__global__ __launch_bounds__(1024) void reduce_decode(
    const float* __restrict__ partial,
    const float* __restrict__ D1, const float* __restrict__ c1,
    const float* __restrict__ D2, const float* __restrict__ c2,
    const float* __restrict__ D3, const float* __restrict__ c3,
    float* __restrict__ out)
{
    __shared__ float red8[8][HD];
    __shared__ float red2[2][HD];
    __shared__ float hb[HD];
    __shared__ float tb[HD];
    const int b = blockIdx.x;
    const int t = threadIdx.x;          // 1024 threads
    const int ch = t & 127, sl = t >> 7;   // slice 0..7

    // Phase A: sum tiles tl = sl, sl+8, ... (unrolled x4 for load batching)
    {
        const float* base = partial + b * TPB * HD + ch;
        float s0 = 0.f, s1 = 0.f, s2 = 0.f, s3 = 0.f;
        int tl = sl;
        for (; tl + 32 <= TPB; tl += 32) {
            s0 += base[(tl     ) * HD];
            s1 += base[(tl +  8) * HD];
            s2 += base[(tl + 16) * HD];
            s3 += base[(tl + 24) * HD];
        }
        for (; tl < TPB; tl += 8) s0 += base[tl * HD];
        red8[sl][ch] = (s0 + s1) + (s2 + s3);
    }
    __syncthreads();
    if (sl == 0) {
        float v = ((red8[0][ch] + red8[1][ch]) + (red8[2][ch] + red8[3][ch]))
                + ((red8[4][ch] + red8[5][ch]) + (red8[6][ch] + red8[7][ch]));
        hb[ch] = fmaxf(v * (1.0f / 65536.0f), 0.0f);
    }
    __syncthreads();

    const int hf = sl & 1;   // for decode phases, threads t<256: hf = t>>7

    // dec layer 1 (split-k over 2 halves, 256 threads)
    if (t < 256) {
        float a = 0.f;
        for (int k = hf * 64; k < hf * 64 + 64; ++k)
            a = fmaf(hb[k], D1[(k << 7) + ch], a);
        red2[hf][ch] = a;
    }
    __syncthreads();
    if (t < 128)
        tb[ch] = fmaxf(red2[0][ch] + red2[1][ch] + c1[ch], 0.0f);
    __syncthreads();

    // dec layer 2
    if (t < 256) {
        float a = 0.f;
        for (int k = hf * 64; k < hf * 64 + 64; ++k)
            a = fmaf(tb[k], D2[(k << 7) + ch], a);
        red2[hf][ch] = a;
    }
    __syncthreads();
    if (t < 128)
        hb[ch] = fmaxf(red2[0][ch] + red2[1][ch] + c2[ch], 0.0f);
    __syncthreads();

    // dec layer 3: out[b] = dot(hb, D3) + c3
    if (t < 128) red2[0][ch] = hb[ch] * D3[ch];
    __syncthreads();
    if (t < 64) {
        float r = red2[0][t] + red2[0][t + 64];
#pragma unroll
        for (int s2 = 1; s2 < 64; s2 <<= 1)
            r += __shfl_xor(r, s2, 64);
        if (t == 0) out[b] = r + c3[0];
    }
}

extern "C" void kernel_launch(void* const* d_in, const int* in_sizes, int n_in,
                              void* d_out, int out_size, void* d_ws, size_t ws_size,
                              hipStream_t stream)
{
    (void)in_sizes; (void)n_in; (void)out_size; (void)ws_size;

    const int*   xcat  = (const int*)  d_in[0];
    const float* xfeat = (const float*)d_in[1];
    const float* emb   = (const float*)d_in[2];
    const float* W1    = (const float*)d_in[3];
    const float* b1    = (const float*)d_in[4];
    const float* W2    = (const float*)d_in[5];
    const float* b2    = (const float*)d_in[6];
    const float* W3    = (const float*)d_in[7];
    const float* b3    = (const float*)d_in[8];
    const float* D1    = (const float*)d_in[9];
    const float* c1    = (const float*)d_in[10];
    const float* D2    = (const float*)d_in[11];
    const float* c2    = (const float*)d_in[12];
    const float* D3    = (const float*)d_in[13];
    const float* c3    = (const float*)d_in[14];
    float* out = (float*)d_out;

    half_t* x   = (half_t*)d_ws;                      // 65536 h
    half_t* pw1 = x + NB * NN * 64;                   // 8192 h
    half_t* pw2 = pw1 + 8 * 2 * 64 * 8;               // 16384 h
    half_t* pw3 = pw2 + 8 * 4 * 64 * 8;               // 16384 h
    unsigned short* lut = (unsigned short*)(pw3 + 8 * 4 * 64 * 8);  // 32896 us
    float* partial = (float*)(lut + NPAIR);           // 4*257*128 f

    prep_kernel<<<405, 256, 0, stream>>>(xcat, xfeat, emb, W1, W2, W3,
                                         x, pw1, pw2, pw3, lut);
    pair_mlp<<<dim3(TPB, NB), 256, 0, stream>>>(x, lut, pw1, b1, pw2, b2, pw3, b3, partial);
    reduce_decode<<<NB, 1024, 0, stream>>>(partial, D1, c1, D2, c2, D3, c3, out);
}

// Round 6
// 109.120 us; speedup vs baseline: 1.6410x; 1.0895x over previous
//
#include <hip/hip_runtime.h>

// Eq2NetSet via fp16 MFMA (16x16x32, fp32 accum).  R11 = exact R8 revert.
// R9 lesson: per-block __threadfence (device-scope release on non-coherent
// XCD L2s) serialized the dispatch -> 103us idle kernel. Kernel boundary is
// the cheap device-wide release; keep 3 kernels.
// R10 lesson: smP-on-smH overlay (LDS 49.6->33.3KB, 4 blocks/CU) required
// +2 barriers and regressed 109->119us: barriers destroy the cross-wave
// MFMA||VALU overlap; 5 barriers is minimal for single-buffer. Occupancy
// gain (3->4 blocks) did not compensate.
// Accounting: ~70-80us of dur_us is the harness's 268MB ws re-poison fill;
// our controllable slice is ~28us.
// R6-R8 base: fp16 pipeline (v_pk_mul_f16 P-build, v_cvt_pkrtz epilogue
// packs, tri_ij LUT), channels = M, pairs = N, 128 triangle pairs/block.
//   L1: H1^T = W1^T (A) @ P^T (B),  K=64
//   L2: H2^T = W2^T @ H1^T,         K=128
//   L3: H3^T = W3^T @ H2^T,         K=128 -> relu -> weighted pair-sum

#define NB 4
#define NN 256
#define HD 128
#define TPB 257      // tiles per batch: 32896 pairs / 128
#define NPAIR 32896  // 256*257/2

typedef _Float16 half_t;
typedef __attribute__((ext_vector_type(8))) _Float16 half8;
typedef __attribute__((ext_vector_type(4))) float f32x4;

// packed fp16 pair from two fp32 (single v_cvt_pkrtz_f16_f32)
__device__ __forceinline__ unsigned pkrtz(float a, float b) {
    return __builtin_bit_cast(unsigned, __builtin_amdgcn_cvt_pkrtz(a, b));
}

__device__ __forceinline__ void tri_ij(int t, int& i, int& j) {
    j = (int)((sqrtf(8.0f * (float)t + 1.0f) - 1.0f) * 0.5f);
    while (((j + 1) * (j + 2) >> 1) <= t) ++j;
    while (((j * (j + 1)) >> 1) > t) --j;
    i = t - ((j * (j + 1)) >> 1);
}

// pack W[fanin][128] into A-fragment-linear fp16: packed[(mt*KQ+kq)*64 + lane][j],
// value = W[kq*32 + (lane>>4)*8 + j][mt*16 + (lane&15)]
__device__ __forceinline__ void pack_w(const float* __restrict__ W, half_t* __restrict__ pw,
                                       int KQ, int u) {
    int l  = u & 63;
    int kq = (u >> 6) % KQ;
    int mt = (u >> 6) / KQ;
    int q = l >> 4, m = l & 15;
    int c = mt * 16 + m;
#pragma unroll
    for (int j = 0; j < 8; ++j) {
        int k = kq * 32 + q * 8 + j;
        pw[u * 8 + j] = (half_t)W[k * 128 + c];
    }
}

__global__ void prep_kernel(const int* __restrict__ xcat,
                            const float* __restrict__ xfeat,
                            const float* __restrict__ emb,
                            const float* __restrict__ W1,
                            const float* __restrict__ W2,
                            const float* __restrict__ W3,
                            half_t* __restrict__ x,
                            half_t* __restrict__ pw1,
                            half_t* __restrict__ pw2,
                            half_t* __restrict__ pw3,
                            unsigned short* __restrict__ lut)
{
    int bid = blockIdx.x;
    int tid = threadIdx.x;
    if (bid < 256) {                       // build x[4][256][64] fp16
        int f = bid * 256 + tid;
        int d = f & 63;
        int nn = f >> 6;                   // b*256+n
        float v;
        if (d < 63) v = emb[xcat[nn] * 63 + d];
        else        v = xfeat[nn];
        x[f] = (half_t)v;
    } else if (bid < 260) {                // W1: 8mt*2kq*64 = 1024 threads
        pack_w(W1, pw1, 2, (bid - 256) * 256 + tid);
    } else if (bid < 268) {                // W2: 8mt*4kq*64 = 2048
        pack_w(W2, pw2, 4, (bid - 260) * 256 + tid);
    } else if (bid < 276) {                // W3
        pack_w(W3, pw3, 4, (bid - 268) * 256 + tid);
    } else {                               // triangle (i,j) LUT: 129 blocks
        int t = (bid - 276) * 256 + tid;
        if (t < NPAIR) {
            int i, j;
            tri_ij(t, i, j);
            lut[t] = (unsigned short)(i | (j << 8));
        }
    }
}

__global__ __launch_bounds__(256, 3) void pair_mlp(
    const half_t* __restrict__ x,
    const unsigned short* __restrict__ lut,
    const half_t* __restrict__ pw1, const float* __restrict__ b1,
    const half_t* __restrict__ pw2, const float* __restrict__ b2,
    const half_t* __restrict__ pw3, const float* __restrict__ b3,
    float* __restrict__ partialOut)
{
    __shared__ half_t smP[128 * 64];    // 16 KB  P^T tile, row=pair, 64 f16 (8 chunks)
    __shared__ half_t smH[128 * 128];   // 32 KB  H tile,   row=pair, 128 f16 (16 chunks)
    __shared__ float smW[128];          // pair weights (1 diag / 2 off-diag)

    const int tid = threadIdx.x;
    const int l = tid & 63;
    const int w = __builtin_amdgcn_readfirstlane(tid >> 6);  // wave 0..3
    const int wm = w >> 1;             // channel half: mt in [wm*4, wm*4+4)
    const int wn = w & 1;              // pair half:    pairs [wn*64, wn*64+64)
    const int q = l >> 4;
    const int m = l & 15;
    const int b = blockIdx.y;
    const int tbase = blockIdx.x * 128;          // triangle index base for this tile
    const half_t* xb = x + (b << 14);
    char* smPc = (char*)smP;
    char* smHc = (char*)smH;

    // ---- build P^T tile: 256 threads, thread = (pair p = tid>>1, half = tid&1) ----
    {
        const int p = tid >> 1;
        const int hf = tid & 1;
        unsigned short ij = lut[tbase + p];
        int i = ij & 255, j = ij >> 8;
        if (hf == 0) smW[p] = (i == j) ? 1.0f : 2.0f;
        const half8* xi = (const half8*)(xb + (i << 6) + hf * 32);
        const half8* xj = (const half8*)(xb + (j << 6) + hf * 32);
#pragma unroll
        for (int c = 0; c < 4; ++c) {
            half8 s = xi[c] * xj[c];           // 4x v_pk_mul_f16
            int chunk = hf * 4 + c;
            int phys = chunk ^ (p & 7);
            *(uint4*)(smPc + p * 128 + phys * 16) = __builtin_bit_cast(uint4, s);
        }
    }
    __syncthreads();

    f32x4 acc[4][4];

    // ---- L1: K=64, B from smP, acc init = b1 (bias fold) ----
#pragma unroll
    for (int mt = 0; mt < 4; ++mt) {
        float4 bv = *(const float4*)(b1 + (wm * 4 + mt) * 16 + q * 4);
        f32x4 init = {bv.x, bv.y, bv.z, bv.w};
#pragma unroll
        for (int nt = 0; nt < 4; ++nt) acc[mt][nt] = init;
    }

#pragma unroll
    for (int kq = 0; kq < 2; ++kq) {
        half8 bfr[4], afr[4];
#pragma unroll
        for (int nt = 0; nt < 4; ++nt) {
            int pair = wn * 64 + nt * 16 + m;
            int phys = (kq * 4 + q) ^ (pair & 7);
            bfr[nt] = *(const half8*)(smPc + pair * 128 + phys * 16);
        }
#pragma unroll
        for (int mt = 0; mt < 4; ++mt)
            afr[mt] = *(const half8*)(pw1 + ((((wm * 4 + mt) * 2 + kq) * 64 + l) << 3));
#pragma unroll
        for (int mt = 0; mt < 4; ++mt)
#pragma unroll
            for (int nt = 0; nt < 4; ++nt)
                acc[mt][nt] = __builtin_amdgcn_mfma_f32_16x16x32_f16(afr[mt], bfr[nt], acc[mt][nt], 0, 0, 0);
    }

    // epilogue L1 -> smH (relu + pkrtz f16 pack), swizzled 8B writes
#pragma unroll
    for (int mt = 0; mt < 4; ++mt) {
        int mtg = wm * 4 + mt;
#pragma unroll
        for (int nt = 0; nt < 4; ++nt) {
            int pair = wn * 64 + nt * 16 + m;
            uint2 sv;
            sv.x = pkrtz(fmaxf(acc[mt][nt][0], 0.f), fmaxf(acc[mt][nt][1], 0.f));
            sv.y = pkrtz(fmaxf(acc[mt][nt][2], 0.f), fmaxf(acc[mt][nt][3], 0.f));
            int chunk = mtg * 2 + (q >> 1);
            int phys = chunk ^ (pair & 15);
            *(uint2*)(smHc + pair * 256 + phys * 16 + (q & 1) * 8) = sv;
        }
    }
    __syncthreads();

    // ---- L2: K=128, B from smH (H1), acc init = b2 ----
#pragma unroll
    for (int mt = 0; mt < 4; ++mt) {
        float4 bv = *(const float4*)(b2 + (wm * 4 + mt) * 16 + q * 4);
        f32x4 init = {bv.x, bv.y, bv.z, bv.w};
#pragma unroll
        for (int nt = 0; nt < 4; ++nt) acc[mt][nt] = init;
    }

#pragma unroll
    for (int kq = 0; kq < 4; ++kq) {
        half8 bfr[4], afr[4];
#pragma unroll
        for (int nt = 0; nt < 4; ++nt) {
            int pair = wn * 64 + nt * 16 + m;
            int phys = (kq * 4 + q) ^ (pair & 15);
            bfr[nt] = *(const half8*)(smHc + pair * 256 + phys * 16);
        }
#pragma unroll
        for (int mt = 0; mt < 4; ++mt)
            afr[mt] = *(const half8*)(pw2 + ((((wm * 4 + mt) * 4 + kq) * 64 + l) << 3));
#pragma unroll
        for (int mt = 0; mt < 4; ++mt)
#pragma unroll
            for (int nt = 0; nt < 4; ++nt)
                acc[mt][nt] = __builtin_amdgcn_mfma_f32_16x16x32_f16(afr[mt], bfr[nt], acc[mt][nt], 0, 0, 0);
    }
    __syncthreads();   // all reads of H1 done before overwriting smH

    // epilogue L2 -> smH (H2)
#pragma unroll
    for (int mt = 0; mt < 4; ++mt) {
        int mtg = wm * 4 + mt;
#pragma unroll
        for (int nt = 0; nt < 4; ++nt) {
            int pair = wn * 64 + nt * 16 + m;
            uint2 sv;
            sv.x = pkrtz(fmaxf(acc[mt][nt][0], 0.f), fmaxf(acc[mt][nt][1], 0.f));
            sv.y = pkrtz(fmaxf(acc[mt][nt][2], 0.f), fmaxf(acc[mt][nt][3], 0.f));
            int chunk = mtg * 2 + (q >> 1);
            int phys = chunk ^ (pair & 15);
            *(uint2*)(smHc + pair * 256 + phys * 16 + (q & 1) * 8) = sv;
        }
    }
    __syncthreads();

    // ---- L3: K=128, B from smH (H2), acc init = b3 ----
#pragma unroll
    for (int mt = 0; mt < 4; ++mt) {
        float4 bv = *(const float4*)(b3 + (wm * 4 + mt) * 16 + q * 4);
        f32x4 init = {bv.x, bv.y, bv.z, bv.w};
#pragma unroll
        for (int nt = 0; nt < 4; ++nt) acc[mt][nt] = init;
    }

#pragma unroll
    for (int kq = 0; kq < 4; ++kq) {
        half8 bfr[4], afr[4];
#pragma unroll
        for (int nt = 0; nt < 4; ++nt) {
            int pair = wn * 64 + nt * 16 + m;
            int phys = (kq * 4 + q) ^ (pair & 15);
            bfr[nt] = *(const half8*)(smHc + pair * 256 + phys * 16);
        }
#pragma unroll
        for (int mt = 0; mt < 4; ++mt)
            afr[mt] = *(const half8*)(pw3 + ((((wm * 4 + mt) * 4 + kq) * 64 + l) << 3));
#pragma unroll
        for (int mt = 0; mt < 4; ++mt)
#pragma unroll
            for (int nt = 0; nt < 4; ++nt)
                acc[mt][nt] = __builtin_amdgcn_mfma_f32_16x16x32_f16(afr[mt], bfr[nt], acc[mt][nt], 0, 0, 0);
    }

    // ---- reduction: relu(h3) * pair-weight, sum over pairs -> LDS -> partial ----
    float wpv[4];
#pragma unroll
    for (int nt = 0; nt < 4; ++nt)
        wpv[nt] = smW[wn * 64 + nt * 16 + m];

    float* smPart = (float*)smP;   // 256 floats; smP dead since L1
#pragma unroll
    for (int mt = 0; mt < 4; ++mt) {
        int mtg = wm * 4 + mt;
        float vs[4];
#pragma unroll
        for (int r = 0; r < 4; ++r) {
            vs[r] = wpv[0] * fmaxf(acc[mt][0][r], 0.f) + wpv[1] * fmaxf(acc[mt][1][r], 0.f)
                  + wpv[2] * fmaxf(acc[mt][2][r], 0.f) + wpv[3] * fmaxf(acc[mt][3][r], 0.f);
#pragma unroll
            for (int s = 1; s < 16; s <<= 1)
                vs[r] += __shfl_xor(vs[r], s, 64);
        }
        if (m == 0) {
            float* p = smPart + wn * HD + mtg * 16 + q * 4;
            p[0] = vs[0]; p[1] = vs[1]; p[2] = vs[2]; p[3] = vs[3];
        }
    }
    __syncthreads();

    if (tid < HD) {
        float v = smPart[tid] + smPart[HD + tid];
        partialOut[(b * TPB + blockIdx.x) * HD + tid] = v;   // coalesced 512B/block
    }
}

// fused reduce + decoder: one block per batch, 1024 threads.
__global__ __launch_bounds__(1024) void reduce_decode(
    const float* __restrict__ partial,
    const float* __restrict__ D1, const float* __restrict__ c1,
    const float* __restrict__ D2, const float* __restrict__ c2,
    const float* __restrict__ D3, const float* __restrict__ c3,
    float* __restrict__ out)
{
    __shared__ float red8[8][HD];
    __shared__ float red2[2][HD];
    __shared__ float hb[HD];
    __shared__ float tb[HD];
    const int b = blockIdx.x;
    const int t = threadIdx.x;          // 1024 threads
    const int ch = t & 127, sl = t >> 7;   // slice 0..7

    // Phase A: sum tiles tl = sl, sl+8, ... (unrolled x4 for load batching)
    {
        const float* base = partial + b * TPB * HD + ch;
        float s0 = 0.f, s1 = 0.f, s2 = 0.f, s3 = 0.f;
        int tl = sl;
        for (; tl + 32 <= TPB; tl += 32) {
            s0 += base[(tl     ) * HD];
            s1 += base[(tl +  8) * HD];
            s2 += base[(tl + 16) * HD];
            s3 += base[(tl + 24) * HD];
        }
        for (; tl < TPB; tl += 8) s0 += base[tl * HD];
        red8[sl][ch] = (s0 + s1) + (s2 + s3);
    }
    __syncthreads();
    if (sl == 0) {
        float v = ((red8[0][ch] + red8[1][ch]) + (red8[2][ch] + red8[3][ch]))
                + ((red8[4][ch] + red8[5][ch]) + (red8[6][ch] + red8[7][ch]));
        hb[ch] = fmaxf(v * (1.0f / 65536.0f), 0.0f);
    }
    __syncthreads();

    const int hf = sl & 1;   // for decode phases, threads t<256: hf = t>>7

    // dec layer 1 (split-k over 2 halves, 256 threads)
    if (t < 256) {
        float a = 0.f;
        for (int k = hf * 64; k < hf * 64 + 64; ++k)
            a = fmaf(hb[k], D1[(k << 7) + ch], a);
        red2[hf][ch] = a;
    }
    __syncthreads();
    if (t < 128)
        tb[ch] = fmaxf(red2[0][ch] + red2[1][ch] + c1[ch], 0.0f);
    __syncthreads();

    // dec layer 2
    if (t < 256) {
        float a = 0.f;
        for (int k = hf * 64; k < hf * 64 + 64; ++k)
            a = fmaf(tb[k], D2[(k << 7) + ch], a);
        red2[hf][ch] = a;
    }
    __syncthreads();
    if (t < 128)
        hb[ch] = fmaxf(red2[0][ch] + red2[1][ch] + c2[ch], 0.0f);
    __syncthreads();

    // dec layer 3: out[b] = dot(hb, D3) + c3
    if (t < 128) red2[0][ch] = hb[ch] * D3[ch];
    __syncthreads();
    if (t < 64) {
        float r = red2[0][t] + red2[0][t + 64];
#pragma unroll
        for (int s2 = 1; s2 < 64; s2 <<= 1)
            r += __shfl_xor(r, s2, 64);
        if (t == 0) out[b] = r + c3[0];
    }
}

extern "C" void kernel_launch(void* const* d_in, const int* in_sizes, int n_in,
                              void* d_out, int out_size, void* d_ws, size_t ws_size,
                              hipStream_t stream)
{
    (void)in_sizes; (void)n_in; (void)out_size; (void)ws_size;

    const int*   xcat  = (const int*)  d_in[0];
    const float* xfeat = (const float*)d_in[1];
    const float* emb   = (const float*)d_in[2];
    const float* W1    = (const float*)d_in[3];
    const float* b1    = (const float*)d_in[4];
    const float* W2    = (const float*)d_in[5];
    const float* b2    = (const float*)d_in[6];
    const float* W3    = (const float*)d_in[7];
    const float* b3    = (const float*)d_in[8];
    const float* D1    = (const float*)d_in[9];
    const float* c1    = (const float*)d_in[10];
    const float* D2    = (const float*)d_in[11];
    const float* c2    = (const float*)d_in[12];
    const float* D3    = (const float*)d_in[13];
    const float* c3    = (const float*)d_in[14];
    float* out = (float*)d_out;

    half_t* x   = (half_t*)d_ws;                      // 65536 h
    half_t* pw1 = x + NB * NN * 64;                   // 8192 h
    half_t* pw2 = pw1 + 8 * 2 * 64 * 8;               // 16384 h
    half_t* pw3 = pw2 + 8 * 4 * 64 * 8;               // 16384 h
    unsigned short* lut = (unsigned short*)(pw3 + 8 * 4 * 64 * 8);  // 32896 us
    float* partial = (float*)(lut + NPAIR);           // 4*257*128 f

    prep_kernel<<<405, 256, 0, stream>>>(xcat, xfeat, emb, W1, W2, W3,
                                         x, pw1, pw2, pw3, lut);
    pair_mlp<<<dim3(TPB, NB), 256, 0, stream>>>(x, lut, pw1, b1, pw2, b2, pw3, b3, partial);
    reduce_decode<<<NB, 1024, 0, stream>>>(partial, D1, c1, D2, c2, D3, c3, out);
}